// Round 3
// baseline (560.250 us; speedup 1.0000x reference)
//
#include <hip/hip_runtime.h>

#define DEV __device__ __forceinline__

typedef __attribute__((ext_vector_type(8))) short short8;
typedef __attribute__((ext_vector_type(4))) float f32x4;

// ---------- constants ----------
#define BB 2
#define SS 2048
#define DD 2048
#define HH 32
#define GG 8
#define HDIM 64

DEV unsigned short f2bf(float f) {
    union { float f; unsigned u; } x; x.f = f;
    unsigned r = x.u + 0x7fff + ((x.u >> 16) & 1);
    return (unsigned short)(r >> 16);
}

DEV void gload_lds16(const void* g, void* l) {
    __builtin_amdgcn_global_load_lds(
        (const __attribute__((address_space(1))) unsigned int*)g,
        (__attribute__((address_space(3))) unsigned int*)l, 16, 0, 0);
}

// ---------- fp32 -> bf16 elementwise ----------
__global__ void cvt_bf16(const float* __restrict__ in, unsigned short* __restrict__ out, int n4) {
    int i = blockIdx.x * blockDim.x + threadIdx.x;
    if (i < n4) {
        float4 v = ((const float4*)in)[i];
        ushort4 o;
        o.x = f2bf(v.x); o.y = f2bf(v.y); o.z = f2bf(v.z); o.w = f2bf(v.w);
        ((ushort4*)out)[i] = o;
    }
}

// ---------- transpose-convert weight: W[K][N] fp32 -> WT[N][K] bf16 ----------
__global__ void wtrans(const float* __restrict__ W, unsigned short* __restrict__ WT, int K, int N) {
    __shared__ float t[32][33];
    int c0 = blockIdx.x * 32;   // N dim
    int r0 = blockIdx.y * 32;   // K dim
    int tx = threadIdx.x & 31, ty = threadIdx.x >> 5;  // 256 thr: ty 0..7
    for (int i = 0; i < 4; ++i)
        t[ty + 8*i][tx] = W[(size_t)(r0 + ty + 8*i) * N + c0 + tx];
    __syncthreads();
    for (int i = 0; i < 4; ++i)
        WT[(size_t)(c0 + ty + 8*i) * K + r0 + tx] = f2bf(t[tx][ty + 8*i]);
}

// ---------- GEMM: C[M,N] = A[M,K] @ BT[N,K]^T + bias ----------
// MODE 1: f32 out row-major [M,N] to outQ (O-projection)
// MODE 3: fused QKV epilogue over N=3072 fused cols:
//         cols [0,2048)    -> outQ bf16 row-major stride 2048, biasQ
//         cols [2048,2560) -> outK bf16 row-major stride 512,  biasK
//         cols [2560,3072) -> outV bf16 transposed scatter VT[b][g][d][s], biasV
template<int MODE>
__global__ __launch_bounds__(256, 2)
void gemm_bt(const unsigned short* __restrict__ A, const unsigned short* __restrict__ BT,
             const float* __restrict__ biasQ, const float* __restrict__ biasK,
             const float* __restrict__ biasV,
             void* __restrict__ outQ, void* __restrict__ outK, void* __restrict__ outV,
             int M, int N, int K) {
    __shared__ unsigned short sm[2 * 8192];  // [buf][A:4096 | B:4096] ushorts = 32 KB

    const int tid = threadIdx.x;
    const int l = tid & 63, w = tid >> 6;
    const int wr = w >> 1, wc = w & 1;
    const int fr = l & 15, fk = l >> 4;

    const int ntn = N >> 7;
    const int nwg = gridDim.x;
    int bid = blockIdx.x;
    // XCD swizzle (all our grids are divisible by 8)
    int swz = (bid & 7) * (nwg >> 3) + (bid >> 3);
    const int tm = swz / ntn, tn = swz % ntn;
    const int row0 = tm << 7, col0 = tn << 7;

    f32x4 acc[4][4] = {};

    const int nk = K >> 5;

    // staging: linear LDS dest, inverse-swizzled global source
    #define STAGE(buf, kt)                                                              \
    {                                                                                   \
        const int k0_ = (kt) << 5;                                                      \
        for (int p = 0; p < 2; ++p) {                                                   \
            int Lw = p * 4096 + w * 1024;                                               \
            int Lb = Lw + l * 16;                                                       \
            int r_ = Lb >> 6;                                                           \
            int cs = ((Lb ^ (((r_ >> 1) & 3) << 4)) >> 1) & 31;                         \
            gload_lds16(A + (size_t)(row0 + r_) * K + k0_ + cs,                         \
                        &sm[(buf) * 8192 + (Lw >> 1)]);                                 \
        }                                                                               \
        for (int p = 0; p < 2; ++p) {                                                   \
            int Lw = p * 4096 + w * 1024;                                               \
            int Lb = Lw + l * 16;                                                       \
            int r_ = Lb >> 6;                                                           \
            int cs = ((Lb ^ (((r_ >> 1) & 3) << 4)) >> 1) & 31;                         \
            gload_lds16(BT + (size_t)(col0 + r_) * K + k0_ + cs,                        \
                        &sm[(buf) * 8192 + 4096 + (Lw >> 1)]);                          \
        }                                                                               \
    }

    STAGE(0, 0);
    __syncthreads();

    for (int kt = 0; kt < nk; ++kt) {
        int buf = kt & 1;
        if (kt + 1 < nk) STAGE(buf ^ 1, kt + 1);

        short8 af[4], bfr[4];
        for (int mb = 0; mb < 4; ++mb) {
            int rowloc = wr * 64 + mb * 16 + fr;
            int byte = rowloc * 64 + fk * 16;
            byte ^= ((rowloc >> 1) & 3) << 4;
            af[mb] = *(const short8*)&sm[buf * 8192 + (byte >> 1)];
        }
        for (int nb = 0; nb < 4; ++nb) {
            int rowloc = wc * 64 + nb * 16 + fr;
            int byte = rowloc * 64 + fk * 16;
            byte ^= ((rowloc >> 1) & 3) << 4;
            bfr[nb] = *(const short8*)&sm[buf * 8192 + 4096 + (byte >> 1)];
        }
        for (int mb = 0; mb < 4; ++mb)
            for (int nb = 0; nb < 4; ++nb)
                acc[mb][nb] = __builtin_amdgcn_mfma_f32_16x16x32_bf16(af[mb], bfr[nb], acc[mb][nb], 0, 0, 0);
        __syncthreads();
    }
    #undef STAGE

    const int crow = row0 + wr * 64, ccol = col0 + wc * 64;
    // block-uniform output segment for MODE 3 (segments are 512-aligned, tiles 128-wide)
    for (int mb = 0; mb < 4; ++mb) {
        for (int nb = 0; nb < 4; ++nb) {
            int r = crow + mb * 16 + fk * 4;
            int c = ccol + nb * 16 + fr;
            if (MODE == 1) {
                float* C = (float*)outQ;
                float bv = biasQ[c];
                for (int j = 0; j < 4; ++j)
                    C[(size_t)(r + j) * N + c] = acc[mb][nb][j] + bv;
            } else {  // MODE 3
                if (c < 2048) {
                    unsigned short* C = (unsigned short*)outQ;
                    float bv = biasQ[c];
                    for (int j = 0; j < 4; ++j)
                        C[(size_t)(r + j) * 2048 + c] = f2bf(acc[mb][nb][j] + bv);
                } else if (c < 2560) {
                    int c2 = c - 2048;
                    unsigned short* C = (unsigned short*)outK;
                    float bv = biasK[c2];
                    for (int j = 0; j < 4; ++j)
                        C[(size_t)(r + j) * 512 + c2] = f2bf(acc[mb][nb][j] + bv);
                } else {
                    // transposed scatter: VT[((b*8+g)*64+dd)][s], bf16, pack 4 consecutive s
                    int c2 = c - 2560;
                    unsigned short* VT = (unsigned short*)outV;
                    float bv = biasV[c2];
                    int b_ = r >> 11, s_ = r & 2047;
                    int g_ = c2 >> 6, dd = c2 & 63;
                    ushort4 pk;
                    pk.x = f2bf(acc[mb][nb][0] + bv);
                    pk.y = f2bf(acc[mb][nb][1] + bv);
                    pk.z = f2bf(acc[mb][nb][2] + bv);
                    pk.w = f2bf(acc[mb][nb][3] + bv);
                    *(ushort4*)&VT[(((size_t)b_ * 8 + g_) * 64 + dd) * 2048 + s_] = pk;
                }
            }
        }
    }
}

// ---------- flash attention ----------
// grid: (S/128, H, B), block 256 (4 waves x 32 q-rows)
// Q: [B,S,2048] bf16 ; Kc: [B,S,512] bf16 ; VT: [B,G,64,S] bf16 ; ctx: [B,S,2048] bf16
__global__ __launch_bounds__(256, 2)
void attn(const unsigned short* __restrict__ Q, const unsigned short* __restrict__ Kc,
          const unsigned short* __restrict__ VT, const int* __restrict__ mask,
          unsigned short* __restrict__ ctx) {
    const int qt = blockIdx.x, h = blockIdx.y, b = blockIdx.z;
    const int g = h >> 2;
    const int tid = threadIdx.x;
    const int l = tid & 63, w = tid >> 6;
    const int fr = l & 15, fk = l >> 4;
    const int q0 = qt * 128 + w * 32;

    __shared__ unsigned short plds[4][32 * 64];  // per-wave P tile [32 q][64 k], swizzled

    // Q fragments in registers (A-operand): row fr, k = ks*32 + fk*8
    short8 qf[2][2];
    for (int mb = 0; mb < 2; ++mb)
        for (int ks = 0; ks < 2; ++ks)
            qf[mb][ks] = *(const short8*)&Q[(size_t)(b * SS + q0 + mb * 16 + fr) * DD + h * 64 + ks * 32 + fk * 8];

    float mrun[2][4], lrun[2][4];
    f32x4 oacc[2][4] = {};
    for (int mb = 0; mb < 2; ++mb)
        for (int j = 0; j < 4; ++j) { mrun[mb][j] = -INFINITY; lrun[mb][j] = 0.f; }

    const float scale = 0.125f;  // 1/sqrt(64)

    for (int kt = 0; kt < SS / 64; ++kt) {
        const int j0 = kt * 64;

        // K fragments (B-operand for QK^T): col fr -> key j0+nb*16+fr, k = d
        short8 kf[4][2];
        for (int nb = 0; nb < 4; ++nb)
            for (int ks = 0; ks < 2; ++ks)
                kf[nb][ks] = *(const short8*)&Kc[(size_t)(b * SS + j0 + nb * 16 + fr) * 512 + g * 64 + ks * 32 + fk * 8];
        int mk[4];
        for (int nb = 0; nb < 4; ++nb) mk[nb] = mask[b * SS + j0 + nb * 16 + fr];

        f32x4 s[2][4] = {};
        for (int mb = 0; mb < 2; ++mb)
            for (int nb = 0; nb < 4; ++nb)
                for (int ks = 0; ks < 2; ++ks)
                    s[mb][nb] = __builtin_amdgcn_mfma_f32_16x16x32_bf16(qf[mb][ks], kf[nb][ks], s[mb][nb], 0, 0, 0);

        for (int mb = 0; mb < 2; ++mb)
            for (int nb = 0; nb < 4; ++nb) {
                if (mk[nb] == 0)
                    for (int j = 0; j < 4; ++j) s[mb][nb][j] = -INFINITY;
                else
                    for (int j = 0; j < 4; ++j) s[mb][nb][j] *= scale;
            }

        // online softmax (16-lane xor groups reduce over the 64 keys; each
        // lane keeps stats for its own 4 rows fk*4+j)
        float fsc[2][4];
        for (int mb = 0; mb < 2; ++mb)
            for (int j = 0; j < 4; ++j) {
                float t = fmaxf(fmaxf(s[mb][0][j], s[mb][1][j]), fmaxf(s[mb][2][j], s[mb][3][j]));
                for (int d = 1; d < 16; d <<= 1) t = fmaxf(t, __shfl_xor(t, d, 64));
                float mn = fmaxf(mrun[mb][j], t);
                fsc[mb][j] = __expf(mrun[mb][j] - mn);
                mrun[mb][j] = mn;
            }

        for (int mb = 0; mb < 2; ++mb) {
            float ls[4] = {0.f, 0.f, 0.f, 0.f};
            for (int nb = 0; nb < 4; ++nb)
                for (int j = 0; j < 4; ++j) {
                    float p = __expf(s[mb][nb][j] - mrun[mb][j]);
                    ls[j] += p;
                    int row = mb * 16 + fk * 4 + j, col = nb * 16 + fr;
                    int byte = (row << 7) + (col << 1);
                    byte ^= (row & 7) << 4;
                    plds[w][byte >> 1] = f2bf(p);
                }
            for (int j = 0; j < 4; ++j) {
                float t = ls[j];
                for (int d = 1; d < 16; d <<= 1) t += __shfl_xor(t, d, 64);
                lrun[mb][j] = lrun[mb][j] * fsc[mb][j] + t;
            }
            for (int db = 0; db < 4; ++db)
                for (int j = 0; j < 4; ++j) oacc[mb][db][j] *= fsc[mb][j];
        }
        __syncthreads();

        // PV: A = P (from plds), B = V (VT rows contiguous in s)
        short8 pf[2][2], vf[4][2];
        for (int mb = 0; mb < 2; ++mb)
            for (int ks = 0; ks < 2; ++ks) {
                int row = mb * 16 + fr;
                int byte = row * 128 + ks * 64 + fk * 16;
                byte ^= (row & 7) << 4;
                pf[mb][ks] = *(const short8*)&plds[w][byte >> 1];
            }
        for (int db = 0; db < 4; ++db)
            for (int ks = 0; ks < 2; ++ks)
                vf[db][ks] = *(const short8*)&VT[(size_t)((b * 8 + g) * 64 + db * 16 + fr) * SS + j0 + ks * 32 + fk * 8];
        for (int mb = 0; mb < 2; ++mb)
            for (int db = 0; db < 4; ++db)
                for (int ks = 0; ks < 2; ++ks)
                    oacc[mb][db] = __builtin_amdgcn_mfma_f32_16x16x32_bf16(pf[mb][ks], vf[db][ks], oacc[mb][db], 0, 0, 0);
        __syncthreads();
    }

    for (int mb = 0; mb < 2; ++mb)
        for (int db = 0; db < 4; ++db)
            for (int j = 0; j < 4; ++j) {
                float v = oacc[mb][db][j] / lrun[mb][j];
                ctx[(size_t)(b * SS + q0 + mb * 16 + fk * 4 + j) * DD + h * 64 + db * 16 + fr] = f2bf(v);
            }
}

// ---------- launch ----------
extern "C" void kernel_launch(void* const* d_in, const int* in_sizes, int n_in,
                              void* d_out, int out_size, void* d_ws, size_t ws_size,
                              hipStream_t stream) {
    const float* x   = (const float*)d_in[0];
    const int* mask  = (const int*)d_in[1];
    const float* q_w = (const float*)d_in[2];
    const float* q_b = (const float*)d_in[3];
    const float* k_w = (const float*)d_in[4];
    const float* k_b = (const float*)d_in[5];
    const float* v_w = (const float*)d_in[6];
    const float* v_b = (const float*)d_in[7];
    const float* o_w = (const float*)d_in[8];
    const float* o_b = (const float*)d_in[9];
    float* out = (float*)d_out;

    // workspace layout (60 MB): ctxb aliases xb (xb dead after QKV GEMM,
    // ctxb first written by attn, strictly later on the same stream)
    char* p = (char*)d_ws;
    unsigned short* xb   = (unsigned short*)p; p += (size_t)BB * SS * DD * 2;       // 16 MB
    unsigned short* ctxb = xb;                                                      // alias
    unsigned short* wAll = (unsigned short*)p; p += (size_t)3072 * DD * 2;          // 12 MB (qwT|kwT|vwT)
    unsigned short* owT  = (unsigned short*)p; p += (size_t)DD * DD * 2;            // 8 MB
    unsigned short* Qb   = (unsigned short*)p; p += (size_t)BB * SS * DD * 2;       // 16 MB
    unsigned short* Kb   = (unsigned short*)p; p += (size_t)BB * SS * 512 * 2;      // 4 MB
    unsigned short* VTb  = (unsigned short*)p; p += (size_t)BB * SS * 512 * 2;      // 4 MB

    const int M = BB * SS;  // 4096

    cvt_bf16<<<(M * DD / 4 + 255) / 256, 256, 0, stream>>>(x, xb, M * DD / 4);
    // fused weight: wAll rows [0,2048)=q^T, [2048,2560)=k^T, [2560,3072)=v^T
    wtrans<<<dim3(DD / 32, DD / 32), 256, 0, stream>>>(q_w, wAll, DD, DD);
    wtrans<<<dim3(512 / 32, DD / 32), 256, 0, stream>>>(k_w, wAll + (size_t)2048 * DD, DD, 512);
    wtrans<<<dim3(512 / 32, DD / 32), 256, 0, stream>>>(v_w, wAll + (size_t)2560 * DD, DD, 512);
    wtrans<<<dim3(DD / 32, DD / 32), 256, 0, stream>>>(o_w, owT, DD, DD);

    // fused QKV projection: C[4096,3072] = xb @ wAll^T, segmented epilogue
    gemm_bt<3><<<(M / 128) * (3072 / 128), 256, 0, stream>>>(
        xb, wAll, q_b, k_b, v_b, Qb, Kb, VTb, M, 3072, DD);

    attn<<<dim3(SS / 128, HH, BB), 256, 0, stream>>>(Qb, Kb, VTb, mask, ctxb);

    gemm_bt<1><<<(M / 128) * (DD / 128), 256, 0, stream>>>(
        ctxb, owT, o_b, nullptr, nullptr, out, nullptr, nullptr, M, DD, DD);
}

// Round 6
// 448.991 us; speedup vs baseline: 1.2478x; 1.2478x over previous
//
#include <hip/hip_runtime.h>

#define DEV __device__ __forceinline__

typedef __attribute__((ext_vector_type(8))) short short8;
typedef __attribute__((ext_vector_type(4))) float f32x4;

// ---------- constants ----------
#define BB 2
#define SS 2048
#define DD 2048
#define HH 32
#define GG 8
#define HDIM 64

DEV unsigned short f2bf(float f) {
    union { float f; unsigned u; } x; x.f = f;
    unsigned r = x.u + 0x7fff + ((x.u >> 16) & 1);
    return (unsigned short)(r >> 16);
}

DEV void gload_lds16(const void* g, void* l) {
    __builtin_amdgcn_global_load_lds(
        (const __attribute__((address_space(1))) unsigned int*)g,
        (__attribute__((address_space(3))) unsigned int*)l, 16, 0, 0);
}

// ---------- fp32 -> bf16 elementwise ----------
__global__ void cvt_bf16(const float* __restrict__ in, unsigned short* __restrict__ out, int n4) {
    int i = blockIdx.x * blockDim.x + threadIdx.x;
    if (i < n4) {
        float4 v = ((const float4*)in)[i];
        ushort4 o;
        o.x = f2bf(v.x); o.y = f2bf(v.y); o.z = f2bf(v.z); o.w = f2bf(v.w);
        ((ushort4*)out)[i] = o;
    }
}

// ---------- transpose-convert weight: W[K][N] fp32 -> WT[N][K] bf16 ----------
__global__ void wtrans(const float* __restrict__ W, unsigned short* __restrict__ WT, int K, int N) {
    __shared__ float t[32][33];
    int c0 = blockIdx.x * 32;   // N dim
    int r0 = blockIdx.y * 32;   // K dim
    int tx = threadIdx.x & 31, ty = threadIdx.x >> 5;  // 256 thr: ty 0..7
    for (int i = 0; i < 4; ++i)
        t[ty + 8*i][tx] = W[(size_t)(r0 + ty + 8*i) * N + c0 + tx];
    __syncthreads();
    for (int i = 0; i < 4; ++i)
        WT[(size_t)(c0 + ty + 8*i) * K + r0 + tx] = f2bf(t[tx][ty + 8*i]);
}

// ---------- GEMM: C[M,N] = A[M,K] @ BT[N,K]^T + bias ----------
// MODE 1: f32 out row-major [M,N] to outQ (O-projection)
// MODE 3: fused QKV epilogue over N=3072 fused cols:
//         cols [0,2048)    -> outQ bf16 row-major stride 2048, biasQ
//         cols [2048,2560) -> outK bf16 row-major stride 512,  biasK
//         cols [2560,3072) -> outV bf16 transposed scatter VT[b][g][d][s], biasV
template<int MODE>
__global__ __launch_bounds__(256, 2)
void gemm_bt(const unsigned short* __restrict__ A, const unsigned short* __restrict__ BT,
             const float* __restrict__ biasQ, const float* __restrict__ biasK,
             const float* __restrict__ biasV,
             void* __restrict__ outQ, void* __restrict__ outK, void* __restrict__ outV,
             int M, int N, int K) {
    __shared__ unsigned short sm[2 * 8192];  // [buf][A:4096 | B:4096] ushorts = 32 KB

    const int tid = threadIdx.x;
    const int l = tid & 63, w = tid >> 6;
    const int wr = w >> 1, wc = w & 1;
    const int fr = l & 15, fk = l >> 4;

    const int ntn = N >> 7;
    const int nwg = gridDim.x;
    int bid = blockIdx.x;
    // XCD swizzle (all our grids are divisible by 8)
    int swz = (bid & 7) * (nwg >> 3) + (bid >> 3);
    const int tm = swz / ntn, tn = swz % ntn;
    const int row0 = tm << 7, col0 = tn << 7;

    f32x4 acc[4][4] = {};

    const int nk = K >> 5;

    // staging: linear LDS dest, inverse-swizzled global source
    #define STAGE(buf, kt)                                                              \
    {                                                                                   \
        const int k0_ = (kt) << 5;                                                      \
        for (int p = 0; p < 2; ++p) {                                                   \
            int Lw = p * 4096 + w * 1024;                                               \
            int Lb = Lw + l * 16;                                                       \
            int r_ = Lb >> 6;                                                           \
            int cs = ((Lb ^ (((r_ >> 1) & 3) << 4)) >> 1) & 31;                         \
            gload_lds16(A + (size_t)(row0 + r_) * K + k0_ + cs,                         \
                        &sm[(buf) * 8192 + (Lw >> 1)]);                                 \
        }                                                                               \
        for (int p = 0; p < 2; ++p) {                                                   \
            int Lw = p * 4096 + w * 1024;                                               \
            int Lb = Lw + l * 16;                                                       \
            int r_ = Lb >> 6;                                                           \
            int cs = ((Lb ^ (((r_ >> 1) & 3) << 4)) >> 1) & 31;                         \
            gload_lds16(BT + (size_t)(col0 + r_) * K + k0_ + cs,                        \
                        &sm[(buf) * 8192 + 4096 + (Lw >> 1)]);                          \
        }                                                                               \
    }

    STAGE(0, 0);
    __syncthreads();

    for (int kt = 0; kt < nk; ++kt) {
        int buf = kt & 1;
        if (kt + 1 < nk) STAGE(buf ^ 1, kt + 1);

        short8 af[4], bfr[4];
        for (int mb = 0; mb < 4; ++mb) {
            int rowloc = wr * 64 + mb * 16 + fr;
            int byte = rowloc * 64 + fk * 16;
            byte ^= ((rowloc >> 1) & 3) << 4;
            af[mb] = *(const short8*)&sm[buf * 8192 + (byte >> 1)];
        }
        for (int nb = 0; nb < 4; ++nb) {
            int rowloc = wc * 64 + nb * 16 + fr;
            int byte = rowloc * 64 + fk * 16;
            byte ^= ((rowloc >> 1) & 3) << 4;
            bfr[nb] = *(const short8*)&sm[buf * 8192 + 4096 + (byte >> 1)];
        }
        for (int mb = 0; mb < 4; ++mb)
            for (int nb = 0; nb < 4; ++nb)
                acc[mb][nb] = __builtin_amdgcn_mfma_f32_16x16x32_bf16(af[mb], bfr[nb], acc[mb][nb], 0, 0, 0);
        __syncthreads();
    }
    #undef STAGE

    const int crow = row0 + wr * 64, ccol = col0 + wc * 64;
    // block-uniform output segment for MODE 3 (segments are 512-aligned, tiles 128-wide)
    for (int mb = 0; mb < 4; ++mb) {
        for (int nb = 0; nb < 4; ++nb) {
            int r = crow + mb * 16 + fk * 4;
            int c = ccol + nb * 16 + fr;
            if (MODE == 1) {
                float* C = (float*)outQ;
                float bv = biasQ[c];
                for (int j = 0; j < 4; ++j)
                    C[(size_t)(r + j) * N + c] = acc[mb][nb][j] + bv;
            } else {  // MODE 3
                if (c < 2048) {
                    unsigned short* C = (unsigned short*)outQ;
                    float bv = biasQ[c];
                    for (int j = 0; j < 4; ++j)
                        C[(size_t)(r + j) * 2048 + c] = f2bf(acc[mb][nb][j] + bv);
                } else if (c < 2560) {
                    int c2 = c - 2048;
                    unsigned short* C = (unsigned short*)outK;
                    float bv = biasK[c2];
                    for (int j = 0; j < 4; ++j)
                        C[(size_t)(r + j) * 512 + c2] = f2bf(acc[mb][nb][j] + bv);
                } else {
                    // transposed scatter: VT[((b*8+g)*64+dd)][s], bf16, pack 4 consecutive s
                    int c2 = c - 2560;
                    unsigned short* VT = (unsigned short*)outV;
                    float bv = biasV[c2];
                    int b_ = r >> 11, s_ = r & 2047;
                    int g_ = c2 >> 6, dd = c2 & 63;
                    ushort4 pk;
                    pk.x = f2bf(acc[mb][nb][0] + bv);
                    pk.y = f2bf(acc[mb][nb][1] + bv);
                    pk.z = f2bf(acc[mb][nb][2] + bv);
                    pk.w = f2bf(acc[mb][nb][3] + bv);
                    *(ushort4*)&VT[(((size_t)b_ * 8 + g_) * 64 + dd) * 2048 + s_] = pk;
                }
            }
        }
    }
}

// ---------- flash attention, 2-phase LDS pipeline ----------
// grid: (S/128, H, B), block 256 (4 waves x 32 q-rows, all same head -> shared K/V)
// Q: [B,S,2048] bf16 ; Kc: [B,S,512] bf16 ; VT: [B,G,64,S] bf16 ; ctx: [B,S,2048] bf16
__global__ __launch_bounds__(256, 2)
void attn(const unsigned short* __restrict__ Q, const unsigned short* __restrict__ Kc,
          const unsigned short* __restrict__ VT, const int* __restrict__ mask,
          unsigned short* __restrict__ ctx) {
    const int qt = blockIdx.x, h = blockIdx.y, b = blockIdx.z;
    const int g = h >> 2;
    const int tid = threadIdx.x;
    const int l = tid & 63, w = tid >> 6;
    const int fr = l & 15, fk = l >> 4;
    const int q0 = qt * 128 + w * 32;
    const int bg64 = (b * 8 + g) * 64;

    // K tile [64 key][64 d] bf16 + V tile [64 d][64 s] bf16, both XOR-swizzled,
    // double-buffered; plus per-wave P tile.
    __shared__ unsigned short klds[2][4096];   // 8 KB each
    __shared__ unsigned short vlds[2][4096];
    __shared__ unsigned short plds[4][2048];   // per-wave [32 q][64 k], swizzled

    // stage tile kt into buf: K rows = keys j0+r (d bytes g*128..), V rows = dims (s bytes j0*2..)
    // linear LDS dest (wave-uniform base + lane*16), inverse-swizzled global source (rule 21)
    #define ASTAGE(buf, kt_)                                                             \
    {                                                                                    \
        const int j0_ = (kt_) << 6;                                                      \
        for (int p = 0; p < 2; ++p) {                                                    \
            int Lw = p * 4096 + w * 1024;                                                \
            int Lb = Lw + l * 16;                                                        \
            int r_ = Lb >> 7;                                                            \
            int cs = (Lb & 127) ^ ((r_ & 7) << 4);                                       \
            gload_lds16((const char*)Kc + (size_t)(b * SS + j0_ + r_) * 1024 + g * 128 + cs, \
                        &klds[buf][Lw >> 1]);                                            \
        }                                                                                \
        for (int p = 0; p < 2; ++p) {                                                    \
            int Lw = p * 4096 + w * 1024;                                                \
            int Lb = Lw + l * 16;                                                        \
            int r_ = Lb >> 7;                                                            \
            int cs = (Lb & 127) ^ ((r_ & 7) << 4);                                       \
            gload_lds16((const char*)VT + (size_t)(bg64 + r_) * (SS * 2) + j0_ * 2 + cs, \
                        &vlds[buf][Lw >> 1]);                                            \
        }                                                                                \
    }

    // Q fragments in registers (A-operand): row fr, k = ks*32 + fk*8
    short8 qf[2][2];
    for (int mb = 0; mb < 2; ++mb)
        for (int ks = 0; ks < 2; ++ks)
            qf[mb][ks] = *(const short8*)&Q[(size_t)(b * SS + q0 + mb * 16 + fr) * DD + h * 64 + ks * 32 + fk * 8];

    float mrun[2][4], lrun[2][4];
    f32x4 oacc[2][4] = {};
    for (int mb = 0; mb < 2; ++mb)
        for (int j = 0; j < 4; ++j) { mrun[mb][j] = -INFINITY; lrun[mb][j] = 0.f; }

    const float scale = 0.125f;  // 1/sqrt(64)
    const int NT = SS / 64;

    ASTAGE(0, 0);
    __syncthreads();

    for (int kt = 0; kt < NT; ++kt) {
        const int buf = kt & 1;
        const int j0 = kt * 64;

        // mask loads FIRST (so waiting on them doesn't drain the staging queue)
        int mk[4];
        for (int nb = 0; nb < 4; ++nb) mk[nb] = mask[b * SS + j0 + nb * 16 + fr];

        // prefetch next tile (completes at the loop-end barrier's vmcnt drain)
        if (kt + 1 < NT) ASTAGE(buf ^ 1, kt + 1);

        // K fragments from LDS (B-operand): key col = nb*16+fr, d = ks*32+fk*8
        short8 kf[4][2];
        for (int nb = 0; nb < 4; ++nb)
            for (int ks = 0; ks < 2; ++ks) {
                int rloc = nb * 16 + fr;
                int byte = rloc * 128 + ((ks * 64 + fk * 16) ^ ((rloc & 7) << 4));
                kf[nb][ks] = *(const short8*)&klds[buf][byte >> 1];
            }

        f32x4 s[2][4] = {};
        __builtin_amdgcn_s_setprio(1);
        for (int mb = 0; mb < 2; ++mb)
            for (int nb = 0; nb < 4; ++nb)
                for (int ks = 0; ks < 2; ++ks)
                    s[mb][nb] = __builtin_amdgcn_mfma_f32_16x16x32_bf16(qf[mb][ks], kf[nb][ks], s[mb][nb], 0, 0, 0);
        __builtin_amdgcn_s_setprio(0);

        // V fragments from LDS (independent of softmax -> overlap its VALU work)
        short8 vf[4][2];
        for (int db = 0; db < 4; ++db)
            for (int ks = 0; ks < 2; ++ks) {
                int rloc = db * 16 + fr;
                int byte = rloc * 128 + ((ks * 64 + fk * 16) ^ ((rloc & 7) << 4));
                vf[db][ks] = *(const short8*)&vlds[buf][byte >> 1];
            }

        for (int mb = 0; mb < 2; ++mb)
            for (int nb = 0; nb < 4; ++nb) {
                if (mk[nb] == 0)
                    for (int j = 0; j < 4; ++j) s[mb][nb][j] = -INFINITY;
                else
                    for (int j = 0; j < 4; ++j) s[mb][nb][j] *= scale;
            }

        // online softmax (16-lane xor groups reduce over the 64 keys)
        float fsc[2][4];
        for (int mb = 0; mb < 2; ++mb)
            for (int j = 0; j < 4; ++j) {
                float t = fmaxf(fmaxf(s[mb][0][j], s[mb][1][j]), fmaxf(s[mb][2][j], s[mb][3][j]));
                for (int d = 1; d < 16; d <<= 1) t = fmaxf(t, __shfl_xor(t, d, 64));
                float mn = fmaxf(mrun[mb][j], t);
                fsc[mb][j] = __expf(mrun[mb][j] - mn);
                mrun[mb][j] = mn;
            }

        for (int mb = 0; mb < 2; ++mb) {
            float ls[4] = {0.f, 0.f, 0.f, 0.f};
            for (int nb = 0; nb < 4; ++nb)
                for (int j = 0; j < 4; ++j) {
                    float p = __expf(s[mb][nb][j] - mrun[mb][j]);
                    ls[j] += p;
                    int row = mb * 16 + fk * 4 + j, col = nb * 16 + fr;
                    int byte = (row << 7) + (col << 1);
                    byte ^= (row & 7) << 4;
                    plds[w][byte >> 1] = f2bf(p);
                }
            for (int j = 0; j < 4; ++j) {
                float t = ls[j];
                for (int d = 1; d < 16; d <<= 1) t += __shfl_xor(t, d, 64);
                lrun[mb][j] = lrun[mb][j] * fsc[mb][j] + t;
            }
            for (int db = 0; db < 4; ++db)
                for (int j = 0; j < 4; ++j) oacc[mb][db][j] *= fsc[mb][j];
        }

        // wave-local fence: plds is per-wave, so a full block barrier is overkill.
        // rule 18: sched_barrier(0) after the inline waitcnt so MFMAs aren't hoisted past it.
        asm volatile("s_waitcnt lgkmcnt(0)" ::: "memory");
        __builtin_amdgcn_sched_barrier(0);

        // P fragments (A-operand): row = q, k = ks*32+fk*8
        short8 pf[2][2];
        for (int mb = 0; mb < 2; ++mb)
            for (int ks = 0; ks < 2; ++ks) {
                int row = mb * 16 + fr;
                int byte = row * 128 + ks * 64 + fk * 16;
                byte ^= (row & 7) << 4;
                pf[mb][ks] = *(const short8*)&plds[w][byte >> 1];
            }

        __builtin_amdgcn_s_setprio(1);
        for (int mb = 0; mb < 2; ++mb)
            for (int db = 0; db < 4; ++db)
                for (int ks = 0; ks < 2; ++ks)
                    oacc[mb][db] = __builtin_amdgcn_mfma_f32_16x16x32_bf16(pf[mb][ks], vf[db][ks], oacc[mb][db], 0, 0, 0);
        __builtin_amdgcn_s_setprio(0);

        // single pipeline barrier: (a) all waves done reading buf before next
        // iteration's ASTAGE overwrites it; (b) compiler-emitted vmcnt(0) drain
        // completes the prefetch into buf^1.
        __syncthreads();
    }
    #undef ASTAGE

    for (int mb = 0; mb < 2; ++mb)
        for (int db = 0; db < 4; ++db)
            for (int j = 0; j < 4; ++j) {
                float v = oacc[mb][db][j] / lrun[mb][j];
                ctx[(size_t)(b * SS + q0 + mb * 16 + fk * 4 + j) * DD + h * 64 + db * 16 + fr] = f2bf(v);
            }
}

// ---------- launch ----------
extern "C" void kernel_launch(void* const* d_in, const int* in_sizes, int n_in,
                              void* d_out, int out_size, void* d_ws, size_t ws_size,
                              hipStream_t stream) {
    const float* x   = (const float*)d_in[0];
    const int* mask  = (const int*)d_in[1];
    const float* q_w = (const float*)d_in[2];
    const float* q_b = (const float*)d_in[3];
    const float* k_w = (const float*)d_in[4];
    const float* k_b = (const float*)d_in[5];
    const float* v_w = (const float*)d_in[6];
    const float* v_b = (const float*)d_in[7];
    const float* o_w = (const float*)d_in[8];
    const float* o_b = (const float*)d_in[9];
    float* out = (float*)d_out;

    // workspace layout (60 MB): ctxb aliases xb (xb dead after QKV GEMM,
    // ctxb first written by attn, strictly later on the same stream)
    char* p = (char*)d_ws;
    unsigned short* xb   = (unsigned short*)p; p += (size_t)BB * SS * DD * 2;       // 16 MB
    unsigned short* ctxb = xb;                                                      // alias
    unsigned short* wAll = (unsigned short*)p; p += (size_t)3072 * DD * 2;          // 12 MB (qwT|kwT|vwT)
    unsigned short* owT  = (unsigned short*)p; p += (size_t)DD * DD * 2;            // 8 MB
    unsigned short* Qb   = (unsigned short*)p; p += (size_t)BB * SS * DD * 2;       // 16 MB
    unsigned short* Kb   = (unsigned short*)p; p += (size_t)BB * SS * 512 * 2;      // 4 MB
    unsigned short* VTb  = (unsigned short*)p; p += (size_t)BB * SS * 512 * 2;      // 4 MB

    const int M = BB * SS;  // 4096

    cvt_bf16<<<(M * DD / 4 + 255) / 256, 256, 0, stream>>>(x, xb, M * DD / 4);
    // fused weight: wAll rows [0,2048)=q^T, [2048,2560)=k^T, [2560,3072)=v^T
    wtrans<<<dim3(DD / 32, DD / 32), 256, 0, stream>>>(q_w, wAll, DD, DD);
    wtrans<<<dim3(512 / 32, DD / 32), 256, 0, stream>>>(k_w, wAll + (size_t)2048 * DD, DD, 512);
    wtrans<<<dim3(512 / 32, DD / 32), 256, 0, stream>>>(v_w, wAll + (size_t)2560 * DD, DD, 512);
    wtrans<<<dim3(DD / 32, DD / 32), 256, 0, stream>>>(o_w, owT, DD, DD);

    // fused QKV projection: C[4096,3072] = xb @ wAll^T, segmented epilogue
    gemm_bt<3><<<(M / 128) * (3072 / 128), 256, 0, stream>>>(
        xb, wAll, q_b, k_b, v_b, Qb, Kb, VTb, M, 3072, DD);

    attn<<<dim3(SS / 128, HH, BB), 256, 0, stream>>>(Qb, Kb, VTb, mask, ctxb);

    gemm_bt<1><<<(M / 128) * (DD / 128), 256, 0, stream>>>(
        ctxb, owT, o_b, nullptr, nullptr, out, nullptr, nullptr, M, DD, DD);
}

// Round 7
// 403.263 us; speedup vs baseline: 1.3893x; 1.1134x over previous
//
#include <hip/hip_runtime.h>

#define DEV __device__ __forceinline__

typedef __attribute__((ext_vector_type(8))) short short8;
typedef __attribute__((ext_vector_type(4))) float f32x4;

// ---------- constants ----------
#define BB 2
#define SS 2048
#define DD 2048
#define HH 32
#define GG 8
#define HDIM 64

#if __has_builtin(__builtin_amdgcn_exp2f)
#define EXP2(x) __builtin_amdgcn_exp2f(x)
#else
#define EXP2(x) exp2f(x)
#endif

DEV unsigned short f2bf(float f) {
    union { float f; unsigned u; } x; x.f = f;
    unsigned r = x.u + 0x7fff + ((x.u >> 16) & 1);
    return (unsigned short)(r >> 16);
}

DEV void gload_lds16(const void* g, void* l) {
    __builtin_amdgcn_global_load_lds(
        (const __attribute__((address_space(1))) unsigned int*)g,
        (__attribute__((address_space(3))) unsigned int*)l, 16, 0, 0);
}

// ---------- fp32 -> bf16 elementwise ----------
__global__ void cvt_bf16(const float* __restrict__ in, unsigned short* __restrict__ out, int n4) {
    int i = blockIdx.x * blockDim.x + threadIdx.x;
    if (i < n4) {
        float4 v = ((const float4*)in)[i];
        ushort4 o;
        o.x = f2bf(v.x); o.y = f2bf(v.y); o.z = f2bf(v.z); o.w = f2bf(v.w);
        ((ushort4*)out)[i] = o;
    }
}

// ---------- transpose-convert weight: W[K][N] fp32 -> WT[N][K] bf16 ----------
__global__ void wtrans(const float* __restrict__ W, unsigned short* __restrict__ WT, int K, int N) {
    __shared__ float t[32][33];
    int c0 = blockIdx.x * 32;   // N dim
    int r0 = blockIdx.y * 32;   // K dim
    int tx = threadIdx.x & 31, ty = threadIdx.x >> 5;  // 256 thr: ty 0..7
    for (int i = 0; i < 4; ++i)
        t[ty + 8*i][tx] = W[(size_t)(r0 + ty + 8*i) * N + c0 + tx];
    __syncthreads();
    for (int i = 0; i < 4; ++i)
        WT[(size_t)(c0 + ty + 8*i) * K + r0 + tx] = f2bf(t[tx][ty + 8*i]);
}

// ---------- GEMM: C[M,N] = A[M,K] @ BT[N,K]^T + bias ----------
// MODE 1: f32 out row-major [M,N] to outQ (O-projection)
// MODE 3: fused QKV epilogue over N=3072 fused cols:
//         cols [0,2048)    -> outQ bf16 row-major stride 2048, biasQ
//         cols [2048,2560) -> outK bf16 row-major stride 512,  biasK
//         cols [2560,3072) -> outV bf16 transposed scatter VT[b][g][d][s], biasV
template<int MODE>
__global__ __launch_bounds__(256, 2)
void gemm_bt(const unsigned short* __restrict__ A, const unsigned short* __restrict__ BT,
             const float* __restrict__ biasQ, const float* __restrict__ biasK,
             const float* __restrict__ biasV,
             void* __restrict__ outQ, void* __restrict__ outK, void* __restrict__ outV,
             int M, int N, int K) {
    __shared__ unsigned short sm[2 * 8192];  // [buf][A:4096 | B:4096] ushorts = 32 KB

    const int tid = threadIdx.x;
    const int l = tid & 63, w = tid >> 6;
    const int wr = w >> 1, wc = w & 1;
    const int fr = l & 15, fk = l >> 4;

    const int ntn = N >> 7;
    const int nwg = gridDim.x;
    int bid = blockIdx.x;
    // XCD swizzle (all our grids are divisible by 8)
    int swz = (bid & 7) * (nwg >> 3) + (bid >> 3);
    const int tm = swz / ntn, tn = swz % ntn;
    const int row0 = tm << 7, col0 = tn << 7;

    f32x4 acc[4][4] = {};

    const int nk = K >> 5;

    // staging: linear LDS dest, inverse-swizzled global source
    #define STAGE(buf, kt)                                                              \
    {                                                                                   \
        const int k0_ = (kt) << 5;                                                      \
        for (int p = 0; p < 2; ++p) {                                                   \
            int Lw = p * 4096 + w * 1024;                                               \
            int Lb = Lw + l * 16;                                                       \
            int r_ = Lb >> 6;                                                           \
            int cs = ((Lb ^ (((r_ >> 1) & 3) << 4)) >> 1) & 31;                         \
            gload_lds16(A + (size_t)(row0 + r_) * K + k0_ + cs,                         \
                        &sm[(buf) * 8192 + (Lw >> 1)]);                                 \
        }                                                                               \
        for (int p = 0; p < 2; ++p) {                                                   \
            int Lw = p * 4096 + w * 1024;                                               \
            int Lb = Lw + l * 16;                                                       \
            int r_ = Lb >> 6;                                                           \
            int cs = ((Lb ^ (((r_ >> 1) & 3) << 4)) >> 1) & 31;                         \
            gload_lds16(BT + (size_t)(col0 + r_) * K + k0_ + cs,                        \
                        &sm[(buf) * 8192 + 4096 + (Lw >> 1)]);                          \
        }                                                                               \
    }

    STAGE(0, 0);
    __syncthreads();

    for (int kt = 0; kt < nk; ++kt) {
        int buf = kt & 1;
        if (kt + 1 < nk) STAGE(buf ^ 1, kt + 1);

        short8 af[4], bfr[4];
        for (int mb = 0; mb < 4; ++mb) {
            int rowloc = wr * 64 + mb * 16 + fr;
            int byte = rowloc * 64 + fk * 16;
            byte ^= ((rowloc >> 1) & 3) << 4;
            af[mb] = *(const short8*)&sm[buf * 8192 + (byte >> 1)];
        }
        for (int nb = 0; nb < 4; ++nb) {
            int rowloc = wc * 64 + nb * 16 + fr;
            int byte = rowloc * 64 + fk * 16;
            byte ^= ((rowloc >> 1) & 3) << 4;
            bfr[nb] = *(const short8*)&sm[buf * 8192 + 4096 + (byte >> 1)];
        }
        for (int mb = 0; mb < 4; ++mb)
            for (int nb = 0; nb < 4; ++nb)
                acc[mb][nb] = __builtin_amdgcn_mfma_f32_16x16x32_bf16(af[mb], bfr[nb], acc[mb][nb], 0, 0, 0);
        __syncthreads();
    }
    #undef STAGE

    const int crow = row0 + wr * 64, ccol = col0 + wc * 64;
    // block-uniform output segment for MODE 3 (segments are 512-aligned, tiles 128-wide)
    for (int mb = 0; mb < 4; ++mb) {
        for (int nb = 0; nb < 4; ++nb) {
            int r = crow + mb * 16 + fk * 4;
            int c = ccol + nb * 16 + fr;
            if (MODE == 1) {
                float* C = (float*)outQ;
                float bv = biasQ[c];
                for (int j = 0; j < 4; ++j)
                    C[(size_t)(r + j) * N + c] = acc[mb][nb][j] + bv;
            } else {  // MODE 3
                if (c < 2048) {
                    unsigned short* C = (unsigned short*)outQ;
                    float bv = biasQ[c];
                    for (int j = 0; j < 4; ++j)
                        C[(size_t)(r + j) * 2048 + c] = f2bf(acc[mb][nb][j] + bv);
                } else if (c < 2560) {
                    int c2 = c - 2048;
                    unsigned short* C = (unsigned short*)outK;
                    float bv = biasK[c2];
                    for (int j = 0; j < 4; ++j)
                        C[(size_t)(r + j) * 512 + c2] = f2bf(acc[mb][nb][j] + bv);
                } else {
                    // transposed scatter: VT[((b*8+g)*64+dd)][s], bf16, pack 4 consecutive s
                    int c2 = c - 2560;
                    unsigned short* VT = (unsigned short*)outV;
                    float bv = biasV[c2];
                    int b_ = r >> 11, s_ = r & 2047;
                    int g_ = c2 >> 6, dd = c2 & 63;
                    ushort4 pk;
                    pk.x = f2bf(acc[mb][nb][0] + bv);
                    pk.y = f2bf(acc[mb][nb][1] + bv);
                    pk.z = f2bf(acc[mb][nb][2] + bv);
                    pk.w = f2bf(acc[mb][nb][3] + bv);
                    *(ushort4*)&VT[(((size_t)b_ * 8 + g_) * 64 + dd) * 2048 + s_] = pk;
                }
            }
        }
    }
}

// ---------- flash attention, 2-phase LDS pipeline + lean softmax ----------
// grid: (S/128, H, B), block 256 (4 waves x 32 q-rows, all same head -> shared K/V)
// Q: [B,S,2048] bf16 ; Kc: [B,S,512] bf16 ; VT: [B,G,64,S] bf16 ; ctx: [B,S,2048] bf16
// Softmax in log2 units: scores pre-multiplied by scale*log2e, exp -> v_exp_f32 (native exp2).
// Row-sum via MFMA with ones B-operand (lacc), defer-max with THR=8 (P <= 256).
__global__ __launch_bounds__(256, 2)
void attn(const unsigned short* __restrict__ Q, const unsigned short* __restrict__ Kc,
          const unsigned short* __restrict__ VT, const int* __restrict__ mask,
          unsigned short* __restrict__ ctx) {
    const int qt = blockIdx.x, h = blockIdx.y, b = blockIdx.z;
    const int g = h >> 2;
    const int tid = threadIdx.x;
    const int l = tid & 63, w = tid >> 6;
    const int fr = l & 15, fk = l >> 4;
    const int q0 = qt * 128 + w * 32;
    const int bg64 = (b * 8 + g) * 64;

    __shared__ unsigned short klds[2][4096];   // 8 KB each
    __shared__ unsigned short vlds[2][4096];
    __shared__ unsigned short plds[4][2048];   // per-wave [32 q][64 k], swizzled

    #define ASTAGE(buf, kt_)                                                             \
    {                                                                                    \
        const int j0_ = (kt_) << 6;                                                      \
        for (int p = 0; p < 2; ++p) {                                                    \
            int Lw = p * 4096 + w * 1024;                                                \
            int Lb = Lw + l * 16;                                                        \
            int r_ = Lb >> 7;                                                            \
            int cs = (Lb & 127) ^ ((r_ & 7) << 4);                                       \
            gload_lds16((const char*)Kc + (size_t)(b * SS + j0_ + r_) * 1024 + g * 128 + cs, \
                        &klds[buf][Lw >> 1]);                                            \
        }                                                                                \
        for (int p = 0; p < 2; ++p) {                                                    \
            int Lw = p * 4096 + w * 1024;                                                \
            int Lb = Lw + l * 16;                                                        \
            int r_ = Lb >> 7;                                                            \
            int cs = (Lb & 127) ^ ((r_ & 7) << 4);                                       \
            gload_lds16((const char*)VT + (size_t)(bg64 + r_) * (SS * 2) + j0_ * 2 + cs, \
                        &vlds[buf][Lw >> 1]);                                            \
        }                                                                                \
    }

    // Q fragments in registers (A-operand): row fr, k = ks*32 + fk*8
    short8 qf[2][2];
    for (int mb = 0; mb < 2; ++mb)
        for (int ks = 0; ks < 2; ++ks)
            qf[mb][ks] = *(const short8*)&Q[(size_t)(b * SS + q0 + mb * 16 + fr) * DD + h * 64 + ks * 32 + fk * 8];

    // ones B-fragment (bf16 1.0 = 0x3F80) for the row-sum MFMA
    short8 ones8;
    for (int e = 0; e < 8; ++e) ones8[e] = (short)0x3F80;

    float mrun[2][4];
    f32x4 oacc[2][4] = {};
    f32x4 lacc[2] = {};
    for (int mb = 0; mb < 2; ++mb)
        for (int j = 0; j < 4; ++j) mrun[mb][j] = -INFINITY;

    // log2-rebased scale: 1/sqrt(64) * log2(e)
    const float scale2 = 0.125f * 1.44269504089f;
    const float THR = 8.0f;   // log2 units: deferred P bounded by 2^8 = 256
    const int NT = SS / 64;

    ASTAGE(0, 0);
    __syncthreads();

    for (int kt = 0; kt < NT; ++kt) {
        const int buf = kt & 1;
        const int j0 = kt * 64;

        // mask loads FIRST (so waiting on them doesn't drain the staging queue)
        int mk[4];
        for (int nb = 0; nb < 4; ++nb) mk[nb] = mask[b * SS + j0 + nb * 16 + fr];

        // prefetch next tile (completes at the loop-end barrier's vmcnt drain)
        if (kt + 1 < NT) ASTAGE(buf ^ 1, kt + 1);

        // K fragments from LDS (B-operand): key col = nb*16+fr, d = ks*32+fk*8
        short8 kf[4][2];
        for (int nb = 0; nb < 4; ++nb)
            for (int ks = 0; ks < 2; ++ks) {
                int rloc = nb * 16 + fr;
                int byte = rloc * 128 + ((ks * 64 + fk * 16) ^ ((rloc & 7) << 4));
                kf[nb][ks] = *(const short8*)&klds[buf][byte >> 1];
            }

        f32x4 s[2][4] = {};
        __builtin_amdgcn_s_setprio(1);
        for (int mb = 0; mb < 2; ++mb)
            for (int nb = 0; nb < 4; ++nb)
                for (int ks = 0; ks < 2; ++ks)
                    s[mb][nb] = __builtin_amdgcn_mfma_f32_16x16x32_bf16(qf[mb][ks], kf[nb][ks], s[mb][nb], 0, 0, 0);
        __builtin_amdgcn_s_setprio(0);

        // V fragments from LDS (independent of softmax -> overlap its VALU work)
        short8 vf[4][2];
        for (int db = 0; db < 4; ++db)
            for (int ks = 0; ks < 2; ++ks) {
                int rloc = db * 16 + fr;
                int byte = rloc * 128 + ((ks * 64 + fk * 16) ^ ((rloc & 7) << 4));
                vf[db][ks] = *(const short8*)&vlds[buf][byte >> 1];
            }

        for (int mb = 0; mb < 2; ++mb)
            for (int nb = 0; nb < 4; ++nb) {
                if (mk[nb] == 0)
                    for (int j = 0; j < 4; ++j) s[mb][nb][j] = -INFINITY;
                else
                    for (int j = 0; j < 4; ++j) s[mb][nb][j] *= scale2;
            }

        // per-row tile max (register tree + 16-lane xor reduce over keys)
        float tmax[2][4];
        int exceed = 0;
        for (int mb = 0; mb < 2; ++mb)
            for (int j = 0; j < 4; ++j) {
                float t = fmaxf(fmaxf(s[mb][0][j], s[mb][1][j]), fmaxf(s[mb][2][j], s[mb][3][j]));
                for (int d = 1; d < 16; d <<= 1) t = fmaxf(t, __shfl_xor(t, d, 64));
                tmax[mb][j] = t;
                exceed |= (t > mrun[mb][j] + THR) ? 1 : 0;
            }

        // defer-max: only rescale when some row's max grew past THR (wave-uniform branch)
        if (__any(exceed)) {
            for (int mb = 0; mb < 2; ++mb)
                for (int j = 0; j < 4; ++j) {
                    float mn = fmaxf(mrun[mb][j], tmax[mb][j]);
                    float fsc = EXP2(mrun[mb][j] - mn);   // 0 on first tile (mrun=-inf)
                    mrun[mb][j] = mn;
                    for (int db = 0; db < 4; ++db) oacc[mb][db][j] *= fsc;
                    lacc[mb][j] *= fsc;
                }
        }

        // P = exp2(s - mrun), store bf16 to per-wave LDS tile (swizzled)
        for (int mb = 0; mb < 2; ++mb)
            for (int nb = 0; nb < 4; ++nb)
                for (int j = 0; j < 4; ++j) {
                    float p = EXP2(s[mb][nb][j] - mrun[mb][j]);
                    int row = mb * 16 + fk * 4 + j, col = nb * 16 + fr;
                    int byte = (row << 7) + (col << 1);
                    byte ^= (row & 7) << 4;
                    plds[w][byte >> 1] = f2bf(p);
                }

        // wave-local fence: plds is per-wave; rule 18: sched_barrier after waitcnt
        asm volatile("s_waitcnt lgkmcnt(0)" ::: "memory");
        __builtin_amdgcn_sched_barrier(0);

        // P fragments (A-operand): row = q, k = ks*32+fk*8
        short8 pf[2][2];
        for (int mb = 0; mb < 2; ++mb)
            for (int ks = 0; ks < 2; ++ks) {
                int row = mb * 16 + fr;
                int byte = row * 128 + ks * 64 + fk * 16;
                byte ^= (row & 7) << 4;
                pf[mb][ks] = *(const short8*)&plds[w][byte >> 1];
            }

        __builtin_amdgcn_s_setprio(1);
        for (int mb = 0; mb < 2; ++mb) {
            for (int db = 0; db < 4; ++db)
                for (int ks = 0; ks < 2; ++ks)
                    oacc[mb][db] = __builtin_amdgcn_mfma_f32_16x16x32_bf16(pf[mb][ks], vf[db][ks], oacc[mb][db], 0, 0, 0);
            // row-sum: lacc += P . ones  (replaces 32 shuffle-adds; same C layout as oacc)
            for (int ks = 0; ks < 2; ++ks)
                lacc[mb] = __builtin_amdgcn_mfma_f32_16x16x32_bf16(pf[mb][ks], ones8, lacc[mb], 0, 0, 0);
        }
        __builtin_amdgcn_s_setprio(0);

        // single pipeline barrier: (a) all waves done reading buf before next
        // iteration's ASTAGE overwrites it; (b) compiler-emitted vmcnt(0) drain
        // completes the prefetch into buf^1.
        __syncthreads();
    }
    #undef ASTAGE

    for (int mb = 0; mb < 2; ++mb) {
        for (int db = 0; db < 4; ++db)
            for (int j = 0; j < 4; ++j) {
                float v = oacc[mb][db][j] / lacc[mb][j];
                ctx[(size_t)(b * SS + q0 + mb * 16 + fk * 4 + j) * DD + h * 64 + db * 16 + fr] = f2bf(v);
            }
    }
}

// ---------- launch ----------
extern "C" void kernel_launch(void* const* d_in, const int* in_sizes, int n_in,
                              void* d_out, int out_size, void* d_ws, size_t ws_size,
                              hipStream_t stream) {
    const float* x   = (const float*)d_in[0];
    const int* mask  = (const int*)d_in[1];
    const float* q_w = (const float*)d_in[2];
    const float* q_b = (const float*)d_in[3];
    const float* k_w = (const float*)d_in[4];
    const float* k_b = (const float*)d_in[5];
    const float* v_w = (const float*)d_in[6];
    const float* v_b = (const float*)d_in[7];
    const float* o_w = (const float*)d_in[8];
    const float* o_b = (const float*)d_in[9];
    float* out = (float*)d_out;

    // workspace layout (60 MB): ctxb aliases xb (xb dead after QKV GEMM,
    // ctxb first written by attn, strictly later on the same stream)
    char* p = (char*)d_ws;
    unsigned short* xb   = (unsigned short*)p; p += (size_t)BB * SS * DD * 2;       // 16 MB
    unsigned short* ctxb = xb;                                                      // alias
    unsigned short* wAll = (unsigned short*)p; p += (size_t)3072 * DD * 2;          // 12 MB (qwT|kwT|vwT)
    unsigned short* owT  = (unsigned short*)p; p += (size_t)DD * DD * 2;            // 8 MB
    unsigned short* Qb   = (unsigned short*)p; p += (size_t)BB * SS * DD * 2;       // 16 MB
    unsigned short* Kb   = (unsigned short*)p; p += (size_t)BB * SS * 512 * 2;      // 4 MB
    unsigned short* VTb  = (unsigned short*)p; p += (size_t)BB * SS * 512 * 2;      // 4 MB

    const int M = BB * SS;  // 4096

    cvt_bf16<<<(M * DD / 4 + 255) / 256, 256, 0, stream>>>(x, xb, M * DD / 4);
    // fused weight: wAll rows [0,2048)=q^T, [2048,2560)=k^T, [2560,3072)=v^T
    wtrans<<<dim3(DD / 32, DD / 32), 256, 0, stream>>>(q_w, wAll, DD, DD);
    wtrans<<<dim3(512 / 32, DD / 32), 256, 0, stream>>>(k_w, wAll + (size_t)2048 * DD, DD, 512);
    wtrans<<<dim3(512 / 32, DD / 32), 256, 0, stream>>>(v_w, wAll + (size_t)2560 * DD, DD, 512);
    wtrans<<<dim3(DD / 32, DD / 32), 256, 0, stream>>>(o_w, owT, DD, DD);

    // fused QKV projection: C[4096,3072] = xb @ wAll^T, segmented epilogue
    gemm_bt<3><<<(M / 128) * (3072 / 128), 256, 0, stream>>>(
        xb, wAll, q_b, k_b, v_b, Qb, Kb, VTb, M, 3072, DD);

    attn<<<dim3(SS / 128, HH, BB), 256, 0, stream>>>(Qb, Kb, VTb, mask, ctxb);

    gemm_bt<1><<<(M / 128) * (DD / 128), 256, 0, stream>>>(
        ctxb, owT, o_b, nullptr, nullptr, out, nullptr, nullptr, M, DD, DD);
}

// Round 12
// 348.658 us; speedup vs baseline: 1.6069x; 1.1566x over previous
//
#include <hip/hip_runtime.h>

#define DEV __device__ __forceinline__

typedef __attribute__((ext_vector_type(8))) short short8;
typedef __attribute__((ext_vector_type(4))) float f32x4;

// ---------- constants ----------
#define BB 2
#define SS 2048
#define DD 2048
#define HH 32
#define GG 8
#define HDIM 64

// 1/sqrt(64) * log2(e): Q pre-scaled by this -> QK^T scores are in log2 units
#define SCALE2 0.1803368801111204f

#if __has_builtin(__builtin_amdgcn_exp2f)
#define EXP2(x) __builtin_amdgcn_exp2f(x)
#else
#define EXP2(x) exp2f(x)
#endif

DEV unsigned short f2bf(float f) {
    union { float f; unsigned u; } x; x.f = f;
    unsigned r = x.u + 0x7fff + ((x.u >> 16) & 1);
    return (unsigned short)(r >> 16);
}

DEV void gload_lds16(const void* g, void* l) {
    __builtin_amdgcn_global_load_lds(
        (const __attribute__((address_space(1))) unsigned int*)g,
        (__attribute__((address_space(3))) unsigned int*)l, 16, 0, 0);
}

// ---------- fp32 -> bf16 elementwise ----------
__global__ void cvt_bf16(const float* __restrict__ in, unsigned short* __restrict__ out, int n4) {
    int i = blockIdx.x * blockDim.x + threadIdx.x;
    if (i < n4) {
        float4 v = ((const float4*)in)[i];
        ushort4 o;
        o.x = f2bf(v.x); o.y = f2bf(v.y); o.z = f2bf(v.z); o.w = f2bf(v.w);
        ((ushort4*)out)[i] = o;
    }
}

// ---------- transpose-convert weight: W[K][N] fp32 -> WT[N][K] bf16 ----------
__global__ void wtrans(const float* __restrict__ W, unsigned short* __restrict__ WT, int K, int N) {
    __shared__ float t[32][33];
    int c0 = blockIdx.x * 32;   // N dim
    int r0 = blockIdx.y * 32;   // K dim
    int tx = threadIdx.x & 31, ty = threadIdx.x >> 5;  // 256 thr: ty 0..7
    for (int i = 0; i < 4; ++i)
        t[ty + 8*i][tx] = W[(size_t)(r0 + ty + 8*i) * N + c0 + tx];
    __syncthreads();
    for (int i = 0; i < 4; ++i)
        WT[(size_t)(c0 + ty + 8*i) * K + r0 + tx] = f2bf(t[tx][ty + 8*i]);
}

// ---------- GEMM: C[M,N] = A[M,K] @ BT[N,K]^T + bias ----------
// MODE 1: f32 out row-major [M,N] to outQ (O-projection)
// MODE 3: fused QKV epilogue over N=3072 fused cols:
//         cols [0,2048)    -> outQ bf16 row-major stride 2048, biasQ, PRE-SCALED by SCALE2
//         cols [2048,2560) -> outK bf16 row-major stride 512,  biasK
//         cols [2560,3072) -> outV bf16 transposed scatter VT[b][g][d][s], biasV
// launch_bounds(256,3): force VGPR <= ~170 so 3 blocks/CU fit (12 waves/CU, the
// m97-reference occupancy); (256,2) capped us at 8 waves/CU.
template<int MODE>
__global__ __launch_bounds__(256, 3)
void gemm_bt(const unsigned short* __restrict__ A, const unsigned short* __restrict__ BT,
             const float* __restrict__ biasQ, const float* __restrict__ biasK,
             const float* __restrict__ biasV,
             void* __restrict__ outQ, void* __restrict__ outK, void* __restrict__ outV,
             int M, int N, int K) {
    __shared__ unsigned short sm[2 * 8192];  // [buf][A:4096 | B:4096] ushorts = 32 KB

    const int tid = threadIdx.x;
    const int l = tid & 63, w = tid >> 6;
    const int wr = w >> 1, wc = w & 1;
    const int fr = l & 15, fk = l >> 4;

    const int ntn = N >> 7;
    const int nwg = gridDim.x;
    int bid = blockIdx.x;
    // XCD swizzle (all our grids are divisible by 8)
    int swz = (bid & 7) * (nwg >> 3) + (bid >> 3);
    const int tm = swz / ntn, tn = swz % ntn;
    const int row0 = tm << 7, col0 = tn << 7;

    f32x4 acc[4][4] = {};

    const int nk = K >> 5;

    // staging: linear LDS dest, inverse-swizzled global source
    #define STAGE(buf, kt)                                                              \
    {                                                                                   \
        const int k0_ = (kt) << 5;                                                      \
        for (int p = 0; p < 2; ++p) {                                                   \
            int Lw = p * 4096 + w * 1024;                                               \
            int Lb = Lw + l * 16;                                                       \
            int r_ = Lb >> 6;                                                           \
            int cs = ((Lb ^ (((r_ >> 1) & 3) << 4)) >> 1) & 31;                         \
            gload_lds16(A + (size_t)(row0 + r_) * K + k0_ + cs,                         \
                        &sm[(buf) * 8192 + (Lw >> 1)]);                                 \
        }                                                                               \
        for (int p = 0; p < 2; ++p) {                                                   \
            int Lw = p * 4096 + w * 1024;                                               \
            int Lb = Lw + l * 16;                                                       \
            int r_ = Lb >> 6;                                                           \
            int cs = ((Lb ^ (((r_ >> 1) & 3) << 4)) >> 1) & 31;                         \
            gload_lds16(BT + (size_t)(col0 + r_) * K + k0_ + cs,                        \
                        &sm[(buf) * 8192 + 4096 + (Lw >> 1)]);                          \
        }                                                                               \
    }

    STAGE(0, 0);
    __syncthreads();

    for (int kt = 0; kt < nk; ++kt) {
        int buf = kt & 1;
        if (kt + 1 < nk) STAGE(buf ^ 1, kt + 1);

        short8 af[4], bfr[4];
        for (int mb = 0; mb < 4; ++mb) {
            int rowloc = wr * 64 + mb * 16 + fr;
            int byte = rowloc * 64 + fk * 16;
            byte ^= ((rowloc >> 1) & 3) << 4;
            af[mb] = *(const short8*)&sm[buf * 8192 + (byte >> 1)];
        }
        for (int nb = 0; nb < 4; ++nb) {
            int rowloc = wc * 64 + nb * 16 + fr;
            int byte = rowloc * 64 + fk * 16;
            byte ^= ((rowloc >> 1) & 3) << 4;
            bfr[nb] = *(const short8*)&sm[buf * 8192 + 4096 + (byte >> 1)];
        }
        for (int mb = 0; mb < 4; ++mb)
            for (int nb = 0; nb < 4; ++nb)
                acc[mb][nb] = __builtin_amdgcn_mfma_f32_16x16x32_bf16(af[mb], bfr[nb], acc[mb][nb], 0, 0, 0);
        __syncthreads();
    }
    #undef STAGE

    const int crow = row0 + wr * 64, ccol = col0 + wc * 64;
    // block-uniform output segment for MODE 3 (segments are 512-aligned, tiles 128-wide)
    for (int mb = 0; mb < 4; ++mb) {
        for (int nb = 0; nb < 4; ++nb) {
            int r = crow + mb * 16 + fk * 4;
            int c = ccol + nb * 16 + fr;
            if (MODE == 1) {
                float* C = (float*)outQ;
                float bv = biasQ[c];
                for (int j = 0; j < 4; ++j)
                    C[(size_t)(r + j) * N + c] = acc[mb][nb][j] + bv;
            } else {  // MODE 3
                if (c < 2048) {
                    unsigned short* C = (unsigned short*)outQ;
                    float bv = biasQ[c];
                    for (int j = 0; j < 4; ++j)
                        C[(size_t)(r + j) * 2048 + c] = f2bf((acc[mb][nb][j] + bv) * SCALE2);
                } else if (c < 2560) {
                    int c2 = c - 2048;
                    unsigned short* C = (unsigned short*)outK;
                    float bv = biasK[c2];
                    for (int j = 0; j < 4; ++j)
                        C[(size_t)(r + j) * 512 + c2] = f2bf(acc[mb][nb][j] + bv);
                } else {
                    // transposed scatter: VT[((b*8+g)*64+dd)][s], bf16, pack 4 consecutive s
                    int c2 = c - 2560;
                    unsigned short* VT = (unsigned short*)outV;
                    float bv = biasV[c2];
                    int b_ = r >> 11, s_ = r & 2047;
                    int g_ = c2 >> 6, dd = c2 & 63;
                    ushort4 pk;
                    pk.x = f2bf(acc[mb][nb][0] + bv);
                    pk.y = f2bf(acc[mb][nb][1] + bv);
                    pk.z = f2bf(acc[mb][nb][2] + bv);
                    pk.w = f2bf(acc[mb][nb][3] + bv);
                    *(ushort4*)&VT[(((size_t)b_ * 8 + g_) * 64 + dd) * 2048 + s_] = pk;
                }
            }
        }
    }
}

// ---------- flash attention, 2-phase LDS pipeline + fixed-base softmax ----------
// grid: (S/128, H, B), block 256 (4 waves x 32 q-rows, all same head -> shared K/V)
// Q: [B,S,2048] bf16 PRE-SCALED by SCALE2 ; Kc: [B,S,512] bf16 ; VT: [B,G,64,S] bf16
// Scores arrive in log2 units; softmax base is FIXED (no running max): the constant
// base cancels exactly in oacc/lacc, and fp32 exp2 / bf16 P have ~2^127 headroom vs
// scores of O(10) -> no overflow, identical precision (exponent shift only).
__global__ __launch_bounds__(256, 2)
void attn(const unsigned short* __restrict__ Q, const unsigned short* __restrict__ Kc,
          const unsigned short* __restrict__ VT, const int* __restrict__ mask,
          unsigned short* __restrict__ ctx) {
    const int qt = blockIdx.x, h = blockIdx.y, b = blockIdx.z;
    const int g = h >> 2;
    const int tid = threadIdx.x;
    const int l = tid & 63, w = tid >> 6;
    const int fr = l & 15, fk = l >> 4;
    const int q0 = qt * 128 + w * 32;
    const int bg64 = (b * 8 + g) * 64;

    __shared__ unsigned short klds[2][4096];   // 8 KB each
    __shared__ unsigned short vlds[2][4096];
    __shared__ unsigned short plds[4][2048];   // per-wave [32 q][64 k], swizzled

    #define ASTAGE(buf, kt_)                                                             \
    {                                                                                    \
        const int j0_ = (kt_) << 6;                                                      \
        for (int p = 0; p < 2; ++p) {                                                    \
            int Lw = p * 4096 + w * 1024;                                                \
            int Lb = Lw + l * 16;                                                        \
            int r_ = Lb >> 7;                                                            \
            int cs = (Lb & 127) ^ ((r_ & 7) << 4);                                       \
            gload_lds16((const char*)Kc + (size_t)(b * SS + j0_ + r_) * 1024 + g * 128 + cs, \
                        &klds[buf][Lw >> 1]);                                            \
        }                                                                                \
        for (int p = 0; p < 2; ++p) {                                                    \
            int Lw = p * 4096 + w * 1024;                                                \
            int Lb = Lw + l * 16;                                                        \
            int r_ = Lb >> 7;                                                            \
            int cs = (Lb & 127) ^ ((r_ & 7) << 4);                                       \
            gload_lds16((const char*)VT + (size_t)(bg64 + r_) * (SS * 2) + j0_ * 2 + cs, \
                        &vlds[buf][Lw >> 1]);                                            \
        }                                                                                \
    }

    // Q fragments in registers (A-operand): row fr, k = ks*32 + fk*8
    short8 qf[2][2];
    for (int mb = 0; mb < 2; ++mb)
        for (int ks = 0; ks < 2; ++ks)
            qf[mb][ks] = *(const short8*)&Q[(size_t)(b * SS + q0 + mb * 16 + fr) * DD + h * 64 + ks * 32 + fk * 8];

    // ones B-fragment (bf16 1.0 = 0x3F80) for the row-sum MFMA
    short8 ones8;
    for (int e = 0; e < 8; ++e) ones8[e] = (short)0x3F80;

    f32x4 oacc[2][4] = {};
    f32x4 lacc[2] = {};

    const int NT = SS / 64;

    ASTAGE(0, 0);
    __syncthreads();

    for (int kt = 0; kt < NT; ++kt) {
        const int buf = kt & 1;
        const int j0 = kt * 64;

        // mask loads FIRST (so waiting on them doesn't drain the staging queue)
        int mk[4];
        for (int nb = 0; nb < 4; ++nb) mk[nb] = mask[b * SS + j0 + nb * 16 + fr];

        // prefetch next tile (completes at the loop-end barrier's vmcnt drain)
        if (kt + 1 < NT) ASTAGE(buf ^ 1, kt + 1);

        // K fragments from LDS (B-operand): key col = nb*16+fr, d = ks*32+fk*8
        short8 kf[4][2];
        for (int nb = 0; nb < 4; ++nb)
            for (int ks = 0; ks < 2; ++ks) {
                int rloc = nb * 16 + fr;
                int byte = rloc * 128 + ((ks * 64 + fk * 16) ^ ((rloc & 7) << 4));
                kf[nb][ks] = *(const short8*)&klds[buf][byte >> 1];
            }

        f32x4 s[2][4] = {};
        __builtin_amdgcn_s_setprio(1);
        for (int mb = 0; mb < 2; ++mb)
            for (int nb = 0; nb < 4; ++nb)
                for (int ks = 0; ks < 2; ++ks)
                    s[mb][nb] = __builtin_amdgcn_mfma_f32_16x16x32_bf16(qf[mb][ks], kf[nb][ks], s[mb][nb], 0, 0, 0);
        __builtin_amdgcn_s_setprio(0);

        // V fragments from LDS (independent of softmax -> overlap)
        short8 vf[4][2];
        for (int db = 0; db < 4; ++db)
            for (int ks = 0; ks < 2; ++ks) {
                int rloc = db * 16 + fr;
                int byte = rloc * 128 + ((ks * 64 + fk * 16) ^ ((rloc & 7) << 4));
                vf[db][ks] = *(const short8*)&vlds[buf][byte >> 1];
            }

        // P = exp2(s) (masked -> 0 via exp2(-inf)), bf16, store to per-wave LDS tile
        for (int mb = 0; mb < 2; ++mb)
            for (int nb = 0; nb < 4; ++nb)
                for (int j = 0; j < 4; ++j) {
                    float sv = (mk[nb] == 0) ? -INFINITY : s[mb][nb][j];
                    float p = EXP2(sv);
                    int row = mb * 16 + fk * 4 + j, col = nb * 16 + fr;
                    int byte = (row << 7) + (col << 1);
                    byte ^= (row & 7) << 4;
                    plds[w][byte >> 1] = f2bf(p);
                }

        // wave-local fence: plds is per-wave; rule 18: sched_barrier after waitcnt
        asm volatile("s_waitcnt lgkmcnt(0)" ::: "memory");
        __builtin_amdgcn_sched_barrier(0);

        // P fragments (A-operand): row = q, k = ks*32+fk*8
        short8 pf[2][2];
        for (int mb = 0; mb < 2; ++mb)
            for (int ks = 0; ks < 2; ++ks) {
                int row = mb * 16 + fr;
                int byte = row * 128 + ks * 64 + fk * 16;
                byte ^= (row & 7) << 4;
                pf[mb][ks] = *(const short8*)&plds[w][byte >> 1];
            }

        __builtin_amdgcn_s_setprio(1);
        for (int mb = 0; mb < 2; ++mb) {
            for (int db = 0; db < 4; ++db)
                for (int ks = 0; ks < 2; ++ks)
                    oacc[mb][db] = __builtin_amdgcn_mfma_f32_16x16x32_bf16(pf[mb][ks], vf[db][ks], oacc[mb][db], 0, 0, 0);
            // row-sum: lacc += P . ones (same bf16 P as numerator; base cancels in the ratio)
            for (int ks = 0; ks < 2; ++ks)
                lacc[mb] = __builtin_amdgcn_mfma_f32_16x16x32_bf16(pf[mb][ks], ones8, lacc[mb], 0, 0, 0);
        }
        __builtin_amdgcn_s_setprio(0);

        // single pipeline barrier: (a) all waves done reading buf before next
        // iteration's ASTAGE overwrites it; (b) compiler-emitted vmcnt(0) drain
        // completes the prefetch into buf^1.
        __syncthreads();
    }
    #undef ASTAGE

    for (int mb = 0; mb < 2; ++mb) {
        for (int db = 0; db < 4; ++db)
            for (int j = 0; j < 4; ++j) {
                float v = oacc[mb][db][j] / lacc[mb][j];
                ctx[(size_t)(b * SS + q0 + mb * 16 + fk * 4 + j) * DD + h * 64 + db * 16 + fr] = f2bf(v);
            }
    }
}

// ---------- launch ----------
extern "C" void kernel_launch(void* const* d_in, const int* in_sizes, int n_in,
                              void* d_out, int out_size, void* d_ws, size_t ws_size,
                              hipStream_t stream) {
    const float* x   = (const float*)d_in[0];
    const int* mask  = (const int*)d_in[1];
    const float* q_w = (const float*)d_in[2];
    const float* q_b = (const float*)d_in[3];
    const float* k_w = (const float*)d_in[4];
    const float* k_b = (const float*)d_in[5];
    const float* v_w = (const float*)d_in[6];
    const float* v_b = (const float*)d_in[7];
    const float* o_w = (const float*)d_in[8];
    const float* o_b = (const float*)d_in[9];
    float* out = (float*)d_out;

    // workspace layout (60 MB): ctxb aliases xb (xb dead after QKV GEMM,
    // ctxb first written by attn, strictly later on the same stream)
    char* p = (char*)d_ws;
    unsigned short* xb   = (unsigned short*)p; p += (size_t)BB * SS * DD * 2;       // 16 MB
    unsigned short* ctxb = xb;                                                      // alias
    unsigned short* wAll = (unsigned short*)p; p += (size_t)3072 * DD * 2;          // 12 MB (qwT|kwT|vwT)
    unsigned short* owT  = (unsigned short*)p; p += (size_t)DD * DD * 2;            // 8 MB
    unsigned short* Qb   = (unsigned short*)p; p += (size_t)BB * SS * DD * 2;       // 16 MB
    unsigned short* Kb   = (unsigned short*)p; p += (size_t)BB * SS * 512 * 2;      // 4 MB
    unsigned short* VTb  = (unsigned short*)p; p += (size_t)BB * SS * 512 * 2;      // 4 MB

    const int M = BB * SS;  // 4096

    cvt_bf16<<<(M * DD / 4 + 255) / 256, 256, 0, stream>>>(x, xb, M * DD / 4);
    // fused weight: wAll rows [0,2048)=q^T, [2048,2560)=k^T, [2560,3072)=v^T
    wtrans<<<dim3(DD / 32, DD / 32), 256, 0, stream>>>(q_w, wAll, DD, DD);
    wtrans<<<dim3(512 / 32, DD / 32), 256, 0, stream>>>(k_w, wAll + (size_t)2048 * DD, DD, 512);
    wtrans<<<dim3(512 / 32, DD / 32), 256, 0, stream>>>(v_w, wAll + (size_t)2560 * DD, DD, 512);
    wtrans<<<dim3(DD / 32, DD / 32), 256, 0, stream>>>(o_w, owT, DD, DD);

    // fused QKV projection: C[4096,3072] = xb @ wAll^T, segmented epilogue
    gemm_bt<3><<<(M / 128) * (3072 / 128), 256, 0, stream>>>(
        xb, wAll, q_b, k_b, v_b, Qb, Kb, VTb, M, 3072, DD);

    attn<<<dim3(SS / 128, HH, BB), 256, 0, stream>>>(Qb, Kb, VTb, mask, ctxb);

    gemm_bt<1><<<(M / 128) * (DD / 128), 256, 0, stream>>>(
        ctxb, owT, o_b, nullptr, nullptr, out, nullptr, nullptr, M, DD, DD);
}